// Round 9
// baseline (7410.704 us; speedup 1.0000x reference)
//
#include <hip/hip_runtime.h>
#include <stdint.h>

// ============================================================================
// CharNN: 2-layer GRU char LM (B=64, T=512, V=256, E=H=1024) on MI355X.
// Round 17: r16 + PIPELINED role-2 epilogue gx2 loads (the real floor).
//  * r16 FETCH decomposition: 1.57MB/interval = gx2 786KB + fresh h slabs
//    256KB + G0/X ~0.5MB -> gx2 sc1 reads are HBM reads (~1.1-1.3us each).
//    Role2's epilogue does 12 CHAINED relaxed-atomic loads (hipcc never
//    pipelines atomic loads, r8) -> 12 x ~1.1us ~= 13us = the invariant floor.
//    Untouched in r6-r16; role2 rate-limits every structure. Explains all
//    nulls (r13 pipelined only mm48; r15/r16 changed sync, not the chain).
//  * Fix: 12 gx2 reads as back-to-back inline-asm `global_load_dword ... sc1`
//    (pipelined, 12 outstanding) + ONE s_waitcnt vmcnt(0), AFTER mm48.
//    Each asm load carries a "memory" clobber -- r7/r12's corruption is
//    consistent with clobber-less asm loads hoisting above __syncthreads;
//    the clobber pins them below the dependency wait.
//  * Everything else EXACTLY r16 (passing, 7.37ms): direct peer polling,
//    write-once h rings + plain cached reads, r13 publish drain, gx2 ring-8.
// ============================================================================

namespace {

constexpr int B = 64, T = 512, V = 256, H = 1024, G = 3072;  // G = 3*H
constexpr int NBLK = 192;                 // 64 blocks per role
constexpr int SLAB = 65536;               // f16 elems per h slab (64 b x 1024 j)
constexpr int R1MASK = 127;               // h1 ring depth 128

typedef _Float16 f16;
typedef unsigned long long u64;
typedef f16 f16x8 __attribute__((ext_vector_type(8)));
typedef f16 f16x4 __attribute__((ext_vector_type(4)));
typedef float f32x4 __attribute__((ext_vector_type(4)));

#define MFMA16(av, bv, acc) __builtin_amdgcn_mfma_f32_16x16x32_f16(av, bv, acc, 0, 0, 0)

// ---- plain cached loads (safe: write-once rotating addresses) --------------
__device__ __forceinline__ f16x8 lload16(const f16* p) {
  return *reinterpret_cast<const f16x8*>(p);
}
__device__ __forceinline__ float lload2(const f16* p) { return (float)*p; }

// ---- relaxed agent-scope (MALL, L2-bypass) access helpers ------------------
__device__ __forceinline__ void astore2(f16* p, float v) {
  union { f16 f; unsigned short s; } u;
  u.f = (f16)v;
  __hip_atomic_store(reinterpret_cast<unsigned short*>(p), u.s,
                     __ATOMIC_RELAXED, __HIP_MEMORY_SCOPE_AGENT);
}
__device__ __forceinline__ void astoref(float* p, float v) {
  __hip_atomic_store(p, v, __ATOMIC_RELAXED, __HIP_MEMORY_SCOPE_AGENT);
}
__device__ __forceinline__ void astorei(int* p, int v) {
  __hip_atomic_store(p, v, __ATOMIC_RELAXED, __HIP_MEMORY_SCOPE_AGENT);
}
__device__ __forceinline__ int aloadi(const int* p) {
  return __hip_atomic_load(p, __ATOMIC_RELAXED, __HIP_MEMORY_SCOPE_AGENT);
}
__device__ __forceinline__ void waitge(const int* p, int target) {
  while (aloadi(p) < target) __builtin_amdgcn_s_sleep(1);
}

// ---- pipelinable uncached (sc1) load, pinned by "memory" clobber -----------
// NOT compiler-vmcnt-tracked: caller must s_waitcnt vmcnt(0) before use.
__device__ __forceinline__ void bload_f32(float& d, const float* p) {
  asm volatile("global_load_dword %0, %1, off sc1"
               : "=v"(d) : "v"(p) : "memory");
}

// ---- 48-row x K=1024 MFMA block, plain cached loads, ring-8 prefetch -------
__device__ __forceinline__ void mm48(const f16* a, const f16* wp, f32x4& aR,
                                     f32x4& aZ, f32x4& aN) {
  f16x8 ring[8];
#pragma unroll
  for (int q = 0; q < 8; ++q) ring[q] = lload16(a + q * 2048);
#pragma unroll
  for (int k0 = 0; k0 < 32; ++k0) {
    f16x8 av = ring[k0 & 7];
    if (k0 + 8 < 32) ring[k0 & 7] = lload16(a + (k0 + 8) * 2048);
    const f16* w = wp + k0 * 1728;
    aR = MFMA16(av, *reinterpret_cast<const f16x8*>(w), aR);
    aZ = MFMA16(av, *reinterpret_cast<const f16x8*>(w + 576), aZ);
    aN = MFMA16(av, *reinterpret_cast<const f16x8*>(w + 1152), aN);
  }
}

// ---- fp32 -> fp16 convert (x4 vectorized) ----------------------------------
__global__ void to_f16_4(const float* __restrict__ src, f16* __restrict__ dst,
                         int n4) {
  int i = blockIdx.x * 256 + threadIdx.x;
  if (i >= n4) return;
  float4 v = reinterpret_cast<const float4*>(src)[i];
  f16x4 o = {(f16)v.x, (f16)v.y, (f16)v.z, (f16)v.w};
  reinterpret_cast<f16x4*>(dst)[i] = o;
}

// ---- pack the 3 role weight images -----------------------------------------
// dst[which][bi][k0<32][row<48][kk<32] f16, dense. row = g*16 + jrow,
// j = bi*16 + jrow. which: 0 = W_hh[0], 1 = W_ih[1], 2 = W_hh[1].
__global__ void pack_w(const float* __restrict__ Whh,
                       const float* __restrict__ Wih, f16* __restrict__ dst) {
  const int id = blockIdx.x * 256 + threadIdx.x;  // 1,179,648 vec8 elems
  const int kkq = id & 3;
  const int rr = id >> 2;
  const int row = rr % 48;
  const int rest = rr / 48;
  const int k0 = rest & 31, bi = (rest >> 5) & 63, which = rest >> 11;
  const int g = row >> 4, jrow = row & 15;
  const float* base = (which == 0) ? Whh
                    : (which == 1) ? (Wih + (size_t)G * H)
                                   : (Whh + (size_t)G * H);
  const float* src =
      base + ((size_t)(g * H + bi * 16 + jrow)) * H + k0 * 32 + kkq * 8;
  float4 a = *reinterpret_cast<const float4*>(src);
  float4 b = *reinterpret_cast<const float4*>(src + 4);
  f16x8 o = {(f16)a.x, (f16)a.y, (f16)a.z, (f16)a.w,
             (f16)b.x, (f16)b.y, (f16)b.z, (f16)b.w};
  *reinterpret_cast<f16x8*>(dst + (size_t)id * 8) = o;
}

// ---- pack h0 into ring slab 0 of each layer + zero sync arrays -------------
__global__ void pack_h0f(const float* __restrict__ h0, f16* __restrict__ h1r,
                         f16* __restrict__ h2r, int* __restrict__ bar) {
  if (blockIdx.x == 0 && threadIdx.x < NBLK) {
    bar[threadIdx.x * 16] = 0;  // arrive slots
  }
  const int id = blockIdx.x * 256 + threadIdx.x;  // 131072
  const int layer = id >> 16, b = (id >> 10) & 63, j = id & 1023;
  const size_t a = ((size_t)(j >> 5) * 64 + b) * 32 + (j & 31);
  const f16 v = (f16)h0[id];
  if (layer == 0) h1r[a] = v; else h2r[a] = v;
}

// ---- fp16 GEMM: C[M,N] = A @ B[N,K]^T + bias -------------------------------
// MODE 0: A row-major [M,K], C fp32 [M,N].
// MODE 2: logits. A = h2ring + SLAB (slab t+1 = y2[t], per-t slabs of 65536);
//         bm indexes t; write out[(b*(T-1)+t)*V + n] for t < T-1.
template <int MODE>
__global__ __launch_bounds__(256) void gemm_f16(
    const f16* __restrict__ A, const f16* __restrict__ Bm,
    const float* __restrict__ bias, float* __restrict__ C, int M, int N,
    int K) {
  __shared__ __align__(16) f16 As[64][48], Bs[64][48];

  const int tid = threadIdx.x;
  const int lane = tid & 63, wv = tid >> 6;
  const int bm = blockIdx.y, bn = blockIdx.x;
  const int srow = tid >> 2, sseg = (tid & 3) * 8;

  const f16* pA = (MODE == 2)
                      ? (A + (size_t)bm * 65536 + srow * 32 + sseg)
                      : (A + (size_t)(bm * 64 + srow) * K + sseg);
  const f16* pB = Bm + (size_t)(bn * 64 + srow) * K + sseg;

  f32x4 acc[4];
  const f32x4 zero = {0.f, 0.f, 0.f, 0.f};
#pragma unroll
  for (int nt = 0; nt < 4; ++nt) acc[nt] = zero;

  const int ar = wv * 16 + (lane & 15);
  const int kk = (lane >> 4) * 8;

  const int niter = K / 32;
  for (int ki = 0; ki < niter; ++ki) {
    int4 va = (MODE == 2) ? *reinterpret_cast<const int4*>(pA + ki * 2048)
                          : *reinterpret_cast<const int4*>(pA + ki * 32);
    int4 vb = *reinterpret_cast<const int4*>(pB + ki * 32);
    __syncthreads();
    *reinterpret_cast<int4*>(&As[srow][sseg]) = va;
    *reinterpret_cast<int4*>(&Bs[srow][sseg]) = vb;
    __syncthreads();

    f16x8 av = *reinterpret_cast<const f16x8*>(&As[ar][kk]);
#pragma unroll
    for (int nt = 0; nt < 4; ++nt) {
      f16x8 bv = *reinterpret_cast<const f16x8*>(&Bs[nt * 16 + (lane & 15)][kk]);
      acc[nt] = MFMA16(av, bv, acc[nt]);
    }
  }

  const int rbase = wv * 16 + (lane >> 4) * 4;
  const int cl = lane & 15;
#pragma unroll
  for (int nt = 0; nt < 4; ++nt) {
    const int n = bn * 64 + nt * 16 + cl;
    const float bv = bias[n];
#pragma unroll
    for (int r = 0; r < 4; ++r) {
      const int m = bm * 64 + rbase + r;
      const float v = acc[nt][r] + bv;
      if (MODE == 0) {
        C[(size_t)m * N + n] = v;
      } else {
        const int t = m >> 6, bb = m & 63;
        if (t < T - 1) C[((size_t)(bb * (T - 1) + t)) * V + n] = v;
      }
    }
  }
}

// ---- persistent decoupled 3-role GRU pipeline, direct peer polling ---------
// 192 blocks (role = bx>>6, jb = bx&63).
// role0 interval i (0..511): h1 slab(i) -> slab(i+1).
// role1 interval i (1..512): gx2 slot((i-1)&7) from h1 slab(i).
// role2 interval i (2..513): h2 slab(t=i-2) -> slab(t+1) (= y2[t]).
// arrive[bx*16] = #completed intervals (stores i+1 after interval i).
__global__ __launch_bounds__(256, 1) void gru_persist(
    const f16* __restrict__ pW, const float* __restrict__ G0,
    const int* __restrict__ X, const float* __restrict__ b_hh,
    const float* __restrict__ b_ih, f16* __restrict__ h1ring,
    f16* __restrict__ h2ring, float* __restrict__ gx2, int* __restrict__ bar) {
  __shared__ __align__(16) f16 Wt[55296];  // [k0<32][row<48][kk padded to 36]

  const int tid = threadIdx.x, bx = blockIdx.x;
  const int lane = tid & 63, wv = tid >> 6;
  const int l15 = lane & 15, kq = lane >> 4;
  const int role = bx >> 6, jb = bx & 63;

  int* arrive = bar;

  // ---- stage this block's 96KB W image (dense global -> padded LDS) ----
  {
    const int2* src = reinterpret_cast<const int2*>(pW + (size_t)bx * 49152);
#pragma unroll
    for (int q = 0; q < 48; ++q) {
      const int flat = q * 256 + tid;   // 12288 int2
      const int k0r = flat >> 3, seg = flat & 7;
      *reinterpret_cast<int2*>(&Wt[k0r * 36 + seg * 4]) = src[flat];
    }
  }
  __syncthreads();

  const int j = jb * 16 + l15;
  float br_ = 0.f, bz_ = 0.f, bn_ = 0.f, bxr_ = 0.f, bxz_ = 0.f, bxn_ = 0.f;
  if (role == 0) {
    br_ = b_hh[j]; bz_ = b_hh[H + j]; bn_ = b_hh[2 * H + j];
  } else if (role == 2) {
    br_ = b_hh[G + j]; bz_ = b_hh[G + H + j]; bn_ = b_hh[G + 2 * H + j];
    bxr_ = b_ih[G + j]; bxz_ = b_ih[G + H + j]; bxn_ = b_ih[G + 2 * H + j];
  }

  const int aoff = (wv * 16 + l15) * 32 + kq * 8;
  const f16* wp = Wt + l15 * 36 + kq * 8;  // + k0*1728 + g*576
  const int bB = wv * 16 + kq * 4;
  const size_t hoff = (size_t)(j >> 5) * 2048 + (j & 31);

  const int i0 = (role == 0) ? 0 : (role == 1) ? 1 : 2;
  const int i1 = (role == 0) ? (T - 1) : (role == 1) ? T : (T + 1);

  for (int i = i0; i <= i1; ++i) {
    // ---- direct peer-arrive polling (wave0: main dep; wave1: 2nd dep) ----
    if (tid < 64) {
      if (role == 0) {
        if (i >= 1) waitge(&arrive[(0 * 64 + tid) * 16], i);
      } else if (role == 1) {
        waitge(&arrive[(0 * 64 + tid) * 16], i);
      } else {
        waitge(&arrive[(1 * 64 + tid) * 16], i);
      }
    } else if (tid < 128) {
      const int l = tid - 64;
      if (role == 0) {
        if (i >= 128) waitge(&arrive[(1 * 64 + l) * 16], i - 126);  // h1 WAR
      } else if (role == 1) {
        if (i >= 9) waitge(&arrive[(2 * 64 + l) * 16], i - 6);      // gx2 WAR
      } else {
        if (i > 2) waitge(&arrive[(2 * 64 + l) * 16], i);           // h2 RAW
      }
    }
    __syncthreads();

    if (role == 0) {
      // ---- L1: h1[t=i] : slab(i) -> slab(i+1) ----
      const f16* hin = h1ring + (size_t)(i & R1MASK) * SLAB;
      f16* hout = h1ring + (size_t)((i + 1) & R1MASK) * SLAB;
      f32x4 aR = {0, 0, 0, 0}, aZ = {0, 0, 0, 0}, aN = {0, 0, 0, 0};
      mm48(hin + aoff, wp, aR, aZ, aN);
#pragma unroll
      for (int r = 0; r < 4; ++r) {
        const int b = bB + r;
        const float* gx = G0 + (size_t)X[b * T + i] * G;
        const float xr = gx[j], xz = gx[H + j], xn = gx[2 * H + j];
        const size_t ha = hoff + (size_t)b * 32;
        const float hp = lload2(hin + ha);
        const float rg = 1.f / (1.f + __expf(-(xr + aR[r] + br_)));
        const float zg = 1.f / (1.f + __expf(-(xz + aZ[r] + bz_)));
        const float ng = tanhf(xn + rg * (aN[r] + bn_));
        astore2(hout + ha, (1.f - zg) * ng + zg * hp);
      }
    } else if (role == 1) {
      // ---- GX: gx2[t=i-1] = y1[t] @ W_ih1^T ; y1[t] = h1 slab(i) ----
      const int t = i - 1;
      f32x4 aR = {0, 0, 0, 0}, aZ = {0, 0, 0, 0}, aN = {0, 0, 0, 0};
      mm48(h1ring + (size_t)(i & R1MASK) * SLAB + aoff, wp, aR, aZ, aN);
      float* gdst = gx2 + ((size_t)((t & 7) * 64 + jb)) * 3072;
#pragma unroll
      for (int r = 0; r < 4; ++r) {
        const int b = bB + r;
        astoref(gdst + b * 16 + l15, aR[r]);
        astoref(gdst + 1024 + b * 16 + l15, aZ[r]);
        astoref(gdst + 2048 + b * 16 + l15, aN[r]);
      }
    } else {
      // ---- L2: h2[t=i-2] : slab(t) -> slab(t+1) (= y2[t]) ----
      const int t = i - 2;
      const f16* hin = h2ring + (size_t)t * SLAB;
      f16* hout = h2ring + (size_t)(t + 1) * SLAB;
      const float* gsrc = gx2 + ((size_t)((t & 7) * 64 + jb)) * 3072;
      f32x4 aR = {0, 0, 0, 0}, aZ = {0, 0, 0, 0}, aN = {0, 0, 0, 0};
      mm48(hin + aoff, wp, aR, aZ, aN);
      // ---- THE FIX: 12 gx2 reads issued back-to-back (12 outstanding HBM
      // reads, ~1.3us total) instead of 12 chained atomic loads (~13us).
      float xrv[4], xzv[4], xnv[4];
#pragma unroll
      for (int r = 0; r < 4; ++r) {
        const int b = bB + r;
        bload_f32(xrv[r], gsrc + b * 16 + l15);
        bload_f32(xzv[r], gsrc + 1024 + b * 16 + l15);
        bload_f32(xnv[r], gsrc + 2048 + b * 16 + l15);
      }
      asm volatile("s_waitcnt vmcnt(0)" ::: "memory");
      __builtin_amdgcn_sched_barrier(0);
#pragma unroll
      for (int r = 0; r < 4; ++r) {
        const int b = bB + r;
        const size_t ha = hoff + (size_t)b * 32;
        const float hp = lload2(hin + ha);
        const float rg = 1.f / (1.f + __expf(-(xrv[r] + bxr_ + aR[r] + br_)));
        const float zg = 1.f / (1.f + __expf(-(xzv[r] + bxz_ + aZ[r] + bz_)));
        const float ng = tanhf(xnv[r] + bxn_ + rg * (aN[r] + bn_));
        const float hv = (1.f - zg) * ng + zg * hp;
        astore2(hout + ha, hv);  // sc1 ring write IS y2[t]
      }
    }

    // ---- publish: per-thread drain (r13) -> syncthreads -> arrive ----
    asm volatile("s_waitcnt vmcnt(0)" ::: "memory");
    __builtin_amdgcn_sched_barrier(0);
    __syncthreads();
    if (tid == 0) astorei(&arrive[bx * 16], i + 1);
  }
}

}  // namespace

// ============================================================================
extern "C" void kernel_launch(void* const* d_in, const int* in_sizes, int n_in,
                              void* d_out, int out_size, void* d_ws,
                              size_t ws_size, hipStream_t stream) {
  const int* X = (const int*)d_in[0];
  const float* h0 = (const float*)d_in[1];
  const float* emb = (const float*)d_in[2];
  const float* W_ih = (const float*)d_in[3];
  const float* W_hh = (const float*)d_in[4];
  const float* b_ih = (const float*)d_in[5];
  const float* b_hh = (const float*)d_in[6];
  const float* W_out = (const float*)d_in[7];
  const float* b_out = (const float*)d_in[8];
  float* out = (float*)d_out;
  (void)in_sizes; (void)n_in; (void)out_size; (void)ws_size;

  // ---- workspace (~120 MB) ----
  char* p = (char*)d_ws;
  auto alloc = [&](size_t bytes) {
    char* q = p;
    p += (bytes + 255) & ~(size_t)255;
    return q;
  };
  f16* pW = (f16*)alloc((size_t)3 * 64 * 49152 * 2);   // 18 MB (3 role images)
  float* G0 = (float*)alloc((size_t)V * G * 4);        // 3 MB
  f16* emb16 = (f16*)alloc((size_t)V * H * 2);
  f16* wih0_16 = (f16*)alloc((size_t)G * H * 2);       // 6 MB
  f16* wout16 = (f16*)alloc((size_t)V * H * 2);
  f16* h1ring = (f16*)alloc((size_t)128 * 65536 * 2);  // 16.8 MB (depth-128)
  f16* h2ring = (f16*)alloc((size_t)513 * 65536 * 2);  // 67.2 MB (doubles as y2)
  float* gx2 = (float*)alloc((size_t)8 * 64 * 3072 * 4);  // 6.3 MB (ring-8)
  int* bar = (int*)alloc(65536);  // arrive slots, 64B-strided
  // arrive slots zeroed by pack_h0f (kernel-end writeback publishes).

  // ---- one-time converts / packs / G0 ----
  to_f16_4<<<(V * H / 4 + 255) / 256, 256, 0, stream>>>(emb, emb16, V * H / 4);
  to_f16_4<<<(G * H / 4 + 255) / 256, 256, 0, stream>>>(W_ih, wih0_16,
                                                        G * H / 4);
  to_f16_4<<<(V * H / 4 + 255) / 256, 256, 0, stream>>>(W_out, wout16,
                                                        V * H / 4);
  pack_w<<<4608, 256, 0, stream>>>(W_hh, W_ih, pW);
  pack_h0f<<<512, 256, 0, stream>>>(h0, h1ring, h2ring, bar);
  gemm_f16<0><<<dim3(G / 64, V / 64), 256, 0, stream>>>(emb16, wih0_16, b_ih,
                                                        G0, V, G, H);

  // ---- persistent decoupled pipeline (cooperative: co-residency) ----
  {
    const f16* a0 = pW; const float* a1 = G0; const int* a2 = X;
    const float* a3 = b_hh; const float* a4 = b_ih;
    f16* a5 = h1ring; f16* a6 = h2ring; float* a7 = gx2; int* a8 = bar;
    void* args[] = {&a0, &a1, &a2, &a3, &a4, &a5, &a6, &a7, &a8};
    hipLaunchCooperativeKernel((const void*)gru_persist, dim3(NBLK), dim3(256),
                               args, 0, stream);
  }

  // ---- logits = y2 @ W_out^T + b_out; y2[t] = h2ring slab t+1 ----
  gemm_f16<2><<<dim3(V / 64, T), 256, 0, stream>>>(h2ring + 65536, wout16,
                                                   b_out, out, T * B, V, H);
}

// Round 10
// 6712.395 us; speedup vs baseline: 1.1040x; 1.1040x over previous
//
#include <hip/hip_runtime.h>
#include <stdint.h>

// ============================================================================
// CharNN: 2-layer GRU char LM (B=64, T=512, V=256, E=H=1024) on MI355X.
// Round 18: cut CYCLES on the per-step critical path (DVFS-deflated clock).
//  * r17 null closed the ledger: every single term (loads, barriers, volume,
//    epilogue chain) individually pipelined -> interval still 14us. Cycle
//    audit at 2.4GHz models ~5us; x2.5-3 mismatch across ALL terms points at
//    low DVFS clock (3% util -> min clock). Can't raise clock; can cut cycles:
//    (a) mm48: batch-32 plain cached loads (all 32 outstanding, compiler-
//        tracked waitcnt -> no untracked-asm hazard) vs ring-8's 4 serial
//        latency rounds. Saves ~2700cy per step per role.
//    (b) epilogue operand gathers moved BEFORE mm48 so they complete under
//        its shadow: role0's 2-level X->G0 chain + hp; role2's hp + 12 gx2
//        sc1 asm loads (memory-clobber pinned below the poll/syncthreads;
//        sc1 required: gx2 ring-8 slots are reused addresses).
//        Saves ~1500-2500cy of post-mm48 serial latency.
//  * Sync protocol, rings, peer polling, publish drain: EXACTLY r17 (passing).
// ============================================================================

namespace {

constexpr int B = 64, T = 512, V = 256, H = 1024, G = 3072;  // G = 3*H
constexpr int NBLK = 192;                 // 64 blocks per role
constexpr int SLAB = 65536;               // f16 elems per h slab (64 b x 1024 j)
constexpr int R1MASK = 127;               // h1 ring depth 128

typedef _Float16 f16;
typedef unsigned long long u64;
typedef f16 f16x8 __attribute__((ext_vector_type(8)));
typedef f16 f16x4 __attribute__((ext_vector_type(4)));
typedef float f32x4 __attribute__((ext_vector_type(4)));

#define MFMA16(av, bv, acc) __builtin_amdgcn_mfma_f32_16x16x32_f16(av, bv, acc, 0, 0, 0)

// ---- plain cached loads (safe: write-once rotating addresses) --------------
__device__ __forceinline__ f16x8 lload16(const f16* p) {
  return *reinterpret_cast<const f16x8*>(p);
}
__device__ __forceinline__ float lload2(const f16* p) { return (float)*p; }

// ---- relaxed agent-scope (MALL, L2-bypass) access helpers ------------------
__device__ __forceinline__ void astore2(f16* p, float v) {
  union { f16 f; unsigned short s; } u;
  u.f = (f16)v;
  __hip_atomic_store(reinterpret_cast<unsigned short*>(p), u.s,
                     __ATOMIC_RELAXED, __HIP_MEMORY_SCOPE_AGENT);
}
__device__ __forceinline__ void astoref(float* p, float v) {
  __hip_atomic_store(p, v, __ATOMIC_RELAXED, __HIP_MEMORY_SCOPE_AGENT);
}
__device__ __forceinline__ void astorei(int* p, int v) {
  __hip_atomic_store(p, v, __ATOMIC_RELAXED, __HIP_MEMORY_SCOPE_AGENT);
}
__device__ __forceinline__ int aloadi(const int* p) {
  return __hip_atomic_load(p, __ATOMIC_RELAXED, __HIP_MEMORY_SCOPE_AGENT);
}
__device__ __forceinline__ void waitge(const int* p, int target) {
  while (aloadi(p) < target) __builtin_amdgcn_s_sleep(1);
}

// ---- pipelinable uncached (sc1) load, pinned by "memory" clobber -----------
// NOT compiler-vmcnt-tracked; issued OLDEST, so any later compiler waitcnt is
// conservative-correct. Final drain: asm vmcnt(0) before use.
__device__ __forceinline__ void bload_f32(float& d, const float* p) {
  asm volatile("global_load_dword %0, %1, off sc1"
               : "=v"(d) : "v"(p) : "memory");
}

// ---- 48-row x K=1024 MFMA block: ALL 32 h-loads outstanding ----------------
// Plain cached loads (compiler-tracked): one latency round instead of ring-8's
// four. hv[32] = 128 VGPR live; 1 block/CU so budget (512/wave) is fine.
__device__ __forceinline__ void mm48(const f16* a, const f16* wp, f32x4& aR,
                                     f32x4& aZ, f32x4& aN) {
  f16x8 hv[32];
#pragma unroll
  for (int q = 0; q < 32; ++q) hv[q] = lload16(a + q * 2048);
#pragma unroll
  for (int k0 = 0; k0 < 32; ++k0) {
    const f16* w = wp + k0 * 1728;
    aR = MFMA16(hv[k0], *reinterpret_cast<const f16x8*>(w), aR);
    aZ = MFMA16(hv[k0], *reinterpret_cast<const f16x8*>(w + 576), aZ);
    aN = MFMA16(hv[k0], *reinterpret_cast<const f16x8*>(w + 1152), aN);
  }
}

// ---- fp32 -> fp16 convert (x4 vectorized) ----------------------------------
__global__ void to_f16_4(const float* __restrict__ src, f16* __restrict__ dst,
                         int n4) {
  int i = blockIdx.x * 256 + threadIdx.x;
  if (i >= n4) return;
  float4 v = reinterpret_cast<const float4*>(src)[i];
  f16x4 o = {(f16)v.x, (f16)v.y, (f16)v.z, (f16)v.w};
  reinterpret_cast<f16x4*>(dst)[i] = o;
}

// ---- pack the 3 role weight images -----------------------------------------
// dst[which][bi][k0<32][row<48][kk<32] f16, dense. row = g*16 + jrow,
// j = bi*16 + jrow. which: 0 = W_hh[0], 1 = W_ih[1], 2 = W_hh[1].
__global__ void pack_w(const float* __restrict__ Whh,
                       const float* __restrict__ Wih, f16* __restrict__ dst) {
  const int id = blockIdx.x * 256 + threadIdx.x;  // 1,179,648 vec8 elems
  const int kkq = id & 3;
  const int rr = id >> 2;
  const int row = rr % 48;
  const int rest = rr / 48;
  const int k0 = rest & 31, bi = (rest >> 5) & 63, which = rest >> 11;
  const int g = row >> 4, jrow = row & 15;
  const float* base = (which == 0) ? Whh
                    : (which == 1) ? (Wih + (size_t)G * H)
                                   : (Whh + (size_t)G * H);
  const float* src =
      base + ((size_t)(g * H + bi * 16 + jrow)) * H + k0 * 32 + kkq * 8;
  float4 a = *reinterpret_cast<const float4*>(src);
  float4 b = *reinterpret_cast<const float4*>(src + 4);
  f16x8 o = {(f16)a.x, (f16)a.y, (f16)a.z, (f16)a.w,
             (f16)b.x, (f16)b.y, (f16)b.z, (f16)b.w};
  *reinterpret_cast<f16x8*>(dst + (size_t)id * 8) = o;
}

// ---- pack h0 into ring slab 0 of each layer + zero sync arrays -------------
__global__ void pack_h0f(const float* __restrict__ h0, f16* __restrict__ h1r,
                         f16* __restrict__ h2r, int* __restrict__ bar) {
  if (blockIdx.x == 0 && threadIdx.x < NBLK) {
    bar[threadIdx.x * 16] = 0;  // arrive slots
  }
  const int id = blockIdx.x * 256 + threadIdx.x;  // 131072
  const int layer = id >> 16, b = (id >> 10) & 63, j = id & 1023;
  const size_t a = ((size_t)(j >> 5) * 64 + b) * 32 + (j & 31);
  const f16 v = (f16)h0[id];
  if (layer == 0) h1r[a] = v; else h2r[a] = v;
}

// ---- fp16 GEMM: C[M,N] = A @ B[N,K]^T + bias -------------------------------
// MODE 0: A row-major [M,K], C fp32 [M,N].
// MODE 2: logits. A = h2ring + SLAB (slab t+1 = y2[t], per-t slabs of 65536);
//         bm indexes t; write out[(b*(T-1)+t)*V + n] for t < T-1.
template <int MODE>
__global__ __launch_bounds__(256) void gemm_f16(
    const f16* __restrict__ A, const f16* __restrict__ Bm,
    const float* __restrict__ bias, float* __restrict__ C, int M, int N,
    int K) {
  __shared__ __align__(16) f16 As[64][48], Bs[64][48];

  const int tid = threadIdx.x;
  const int lane = tid & 63, wv = tid >> 6;
  const int bm = blockIdx.y, bn = blockIdx.x;
  const int srow = tid >> 2, sseg = (tid & 3) * 8;

  const f16* pA = (MODE == 2)
                      ? (A + (size_t)bm * 65536 + srow * 32 + sseg)
                      : (A + (size_t)(bm * 64 + srow) * K + sseg);
  const f16* pB = Bm + (size_t)(bn * 64 + srow) * K + sseg;

  f32x4 acc[4];
  const f32x4 zero = {0.f, 0.f, 0.f, 0.f};
#pragma unroll
  for (int nt = 0; nt < 4; ++nt) acc[nt] = zero;

  const int ar = wv * 16 + (lane & 15);
  const int kk = (lane >> 4) * 8;

  const int niter = K / 32;
  for (int ki = 0; ki < niter; ++ki) {
    int4 va = (MODE == 2) ? *reinterpret_cast<const int4*>(pA + ki * 2048)
                          : *reinterpret_cast<const int4*>(pA + ki * 32);
    int4 vb = *reinterpret_cast<const int4*>(pB + ki * 32);
    __syncthreads();
    *reinterpret_cast<int4*>(&As[srow][sseg]) = va;
    *reinterpret_cast<int4*>(&Bs[srow][sseg]) = vb;
    __syncthreads();

    f16x8 av = *reinterpret_cast<const f16x8*>(&As[ar][kk]);
#pragma unroll
    for (int nt = 0; nt < 4; ++nt) {
      f16x8 bv = *reinterpret_cast<const f16x8*>(&Bs[nt * 16 + (lane & 15)][kk]);
      acc[nt] = MFMA16(av, bv, acc[nt]);
    }
  }

  const int rbase = wv * 16 + (lane >> 4) * 4;
  const int cl = lane & 15;
#pragma unroll
  for (int nt = 0; nt < 4; ++nt) {
    const int n = bn * 64 + nt * 16 + cl;
    const float bv = bias[n];
#pragma unroll
    for (int r = 0; r < 4; ++r) {
      const int m = bm * 64 + rbase + r;
      const float v = acc[nt][r] + bv;
      if (MODE == 0) {
        C[(size_t)m * N + n] = v;
      } else {
        const int t = m >> 6, bb = m & 63;
        if (t < T - 1) C[((size_t)(bb * (T - 1) + t)) * V + n] = v;
      }
    }
  }
}

// ---- persistent decoupled 3-role GRU pipeline, direct peer polling ---------
// 192 blocks (role = bx>>6, jb = bx&63).
// role0 interval i (0..511): h1 slab(i) -> slab(i+1).
// role1 interval i (1..512): gx2 slot((i-1)&7) from h1 slab(i).
// role2 interval i (2..513): h2 slab(t=i-2) -> slab(t+1) (= y2[t]).
// arrive[bx*16] = #completed intervals (stores i+1 after interval i).
__global__ __launch_bounds__(256, 1) void gru_persist(
    const f16* __restrict__ pW, const float* __restrict__ G0,
    const int* __restrict__ X, const float* __restrict__ b_hh,
    const float* __restrict__ b_ih, f16* __restrict__ h1ring,
    f16* __restrict__ h2ring, float* __restrict__ gx2, int* __restrict__ bar) {
  __shared__ __align__(16) f16 Wt[55296];  // [k0<32][row<48][kk padded to 36]

  const int tid = threadIdx.x, bx = blockIdx.x;
  const int lane = tid & 63, wv = tid >> 6;
  const int l15 = lane & 15, kq = lane >> 4;
  const int role = bx >> 6, jb = bx & 63;

  int* arrive = bar;

  // ---- stage this block's 96KB W image (dense global -> padded LDS) ----
  {
    const int2* src = reinterpret_cast<const int2*>(pW + (size_t)bx * 49152);
#pragma unroll
    for (int q = 0; q < 48; ++q) {
      const int flat = q * 256 + tid;   // 12288 int2
      const int k0r = flat >> 3, seg = flat & 7;
      *reinterpret_cast<int2*>(&Wt[k0r * 36 + seg * 4]) = src[flat];
    }
  }
  __syncthreads();

  const int j = jb * 16 + l15;
  float br_ = 0.f, bz_ = 0.f, bn_ = 0.f, bxr_ = 0.f, bxz_ = 0.f, bxn_ = 0.f;
  if (role == 0) {
    br_ = b_hh[j]; bz_ = b_hh[H + j]; bn_ = b_hh[2 * H + j];
  } else if (role == 2) {
    br_ = b_hh[G + j]; bz_ = b_hh[G + H + j]; bn_ = b_hh[G + 2 * H + j];
    bxr_ = b_ih[G + j]; bxz_ = b_ih[G + H + j]; bxn_ = b_ih[G + 2 * H + j];
  }

  const int aoff = (wv * 16 + l15) * 32 + kq * 8;
  const f16* wp = Wt + l15 * 36 + kq * 8;  // + k0*1728 + g*576
  const int bB = wv * 16 + kq * 4;
  const size_t hoff = (size_t)(j >> 5) * 2048 + (j & 31);

  const int i0 = (role == 0) ? 0 : (role == 1) ? 1 : 2;
  const int i1 = (role == 0) ? (T - 1) : (role == 1) ? T : (T + 1);

  for (int i = i0; i <= i1; ++i) {
    // ---- direct peer-arrive polling (wave0: main dep; wave1: 2nd dep) ----
    if (tid < 64) {
      if (role == 0) {
        if (i >= 1) waitge(&arrive[(0 * 64 + tid) * 16], i);
      } else if (role == 1) {
        waitge(&arrive[(0 * 64 + tid) * 16], i);
      } else {
        waitge(&arrive[(1 * 64 + tid) * 16], i);
      }
    } else if (tid < 128) {
      const int l = tid - 64;
      if (role == 0) {
        if (i >= 128) waitge(&arrive[(1 * 64 + l) * 16], i - 126);  // h1 WAR
      } else if (role == 1) {
        if (i >= 9) waitge(&arrive[(2 * 64 + l) * 16], i - 6);      // gx2 WAR
      } else {
        if (i > 2) waitge(&arrive[(2 * 64 + l) * 16], i);           // h2 RAW
      }
    }
    __syncthreads();

    if (role == 0) {
      // ---- L1: h1[t=i] : slab(i) -> slab(i+1) ----
      const f16* hin = h1ring + (size_t)(i & R1MASK) * SLAB;
      f16* hout = h1ring + (size_t)((i + 1) & R1MASK) * SLAB;
      // prefetch the whole epilogue gather (X -> G0 chain + hp) BEFORE mm48
      // so the 2-level chain completes under mm48's load shadow.
      float xr[4], xz[4], xn[4], hp[4];
#pragma unroll
      for (int r = 0; r < 4; ++r) {
        const int b = bB + r;
        const float* gx = G0 + (size_t)X[b * T + i] * G;
        xr[r] = gx[j]; xz[r] = gx[H + j]; xn[r] = gx[2 * H + j];
        hp[r] = lload2(hin + hoff + (size_t)b * 32);
      }
      f32x4 aR = {0, 0, 0, 0}, aZ = {0, 0, 0, 0}, aN = {0, 0, 0, 0};
      mm48(hin + aoff, wp, aR, aZ, aN);
#pragma unroll
      for (int r = 0; r < 4; ++r) {
        const int b = bB + r;
        const size_t ha = hoff + (size_t)b * 32;
        const float rg = 1.f / (1.f + __expf(-(xr[r] + aR[r] + br_)));
        const float zg = 1.f / (1.f + __expf(-(xz[r] + aZ[r] + bz_)));
        const float ng = tanhf(xn[r] + rg * (aN[r] + bn_));
        astore2(hout + ha, (1.f - zg) * ng + zg * hp[r]);
      }
    } else if (role == 1) {
      // ---- GX: gx2[t=i-1] = y1[t] @ W_ih1^T ; y1[t] = h1 slab(i) ----
      const int t = i - 1;
      f32x4 aR = {0, 0, 0, 0}, aZ = {0, 0, 0, 0}, aN = {0, 0, 0, 0};
      mm48(h1ring + (size_t)(i & R1MASK) * SLAB + aoff, wp, aR, aZ, aN);
      float* gdst = gx2 + ((size_t)((t & 7) * 64 + jb)) * 3072;
#pragma unroll
      for (int r = 0; r < 4; ++r) {
        const int b = bB + r;
        astoref(gdst + b * 16 + l15, aR[r]);
        astoref(gdst + 1024 + b * 16 + l15, aZ[r]);
        astoref(gdst + 2048 + b * 16 + l15, aN[r]);
      }
    } else {
      // ---- L2: h2[t=i-2] : slab(t) -> slab(t+1) (= y2[t]) ----
      const int t = i - 2;
      const f16* hin = h2ring + (size_t)t * SLAB;
      f16* hout = h2ring + (size_t)(t + 1) * SLAB;
      const float* gsrc = gx2 + ((size_t)((t & 7) * 64 + jb)) * 3072;
      // prefetch BEFORE mm48: hp (plain, fresh slab) + 12 gx2 sc1 asm loads
      // (ring slots are reused addresses -> must bypass caches; memory
      // clobber pins them below the poll/syncthreads; they're oldest in the
      // vm queue so compiler waits stay conservative-correct).
      float hp[4];
#pragma unroll
      for (int r = 0; r < 4; ++r)
        hp[r] = lload2(hin + hoff + (size_t)(bB + r) * 32);
      float xrv[4], xzv[4], xnv[4];
#pragma unroll
      for (int r = 0; r < 4; ++r) {
        const int b = bB + r;
        bload_f32(xrv[r], gsrc + b * 16 + l15);
        bload_f32(xzv[r], gsrc + 1024 + b * 16 + l15);
        bload_f32(xnv[r], gsrc + 2048 + b * 16 + l15);
      }
      f32x4 aR = {0, 0, 0, 0}, aZ = {0, 0, 0, 0}, aN = {0, 0, 0, 0};
      mm48(hin + aoff, wp, aR, aZ, aN);
      asm volatile("s_waitcnt vmcnt(0)" ::: "memory");
      __builtin_amdgcn_sched_barrier(0);
#pragma unroll
      for (int r = 0; r < 4; ++r) {
        const int b = bB + r;
        const size_t ha = hoff + (size_t)b * 32;
        const float rg = 1.f / (1.f + __expf(-(xrv[r] + bxr_ + aR[r] + br_)));
        const float zg = 1.f / (1.f + __expf(-(xzv[r] + bxz_ + aZ[r] + bz_)));
        const float ng = tanhf(xnv[r] + bxn_ + rg * (aN[r] + bn_));
        const float hv = (1.f - zg) * ng + zg * hp[r];
        astore2(hout + ha, hv);  // sc1 ring write IS y2[t]
      }
    }

    // ---- publish: per-thread drain (r13) -> syncthreads -> arrive ----
    asm volatile("s_waitcnt vmcnt(0)" ::: "memory");
    __builtin_amdgcn_sched_barrier(0);
    __syncthreads();
    if (tid == 0) astorei(&arrive[bx * 16], i + 1);
  }
}

}  // namespace

// ============================================================================
extern "C" void kernel_launch(void* const* d_in, const int* in_sizes, int n_in,
                              void* d_out, int out_size, void* d_ws,
                              size_t ws_size, hipStream_t stream) {
  const int* X = (const int*)d_in[0];
  const float* h0 = (const float*)d_in[1];
  const float* emb = (const float*)d_in[2];
  const float* W_ih = (const float*)d_in[3];
  const float* W_hh = (const float*)d_in[4];
  const float* b_ih = (const float*)d_in[5];
  const float* b_hh = (const float*)d_in[6];
  const float* W_out = (const float*)d_in[7];
  const float* b_out = (const float*)d_in[8];
  float* out = (float*)d_out;
  (void)in_sizes; (void)n_in; (void)out_size; (void)ws_size;

  // ---- workspace (~120 MB) ----
  char* p = (char*)d_ws;
  auto alloc = [&](size_t bytes) {
    char* q = p;
    p += (bytes + 255) & ~(size_t)255;
    return q;
  };
  f16* pW = (f16*)alloc((size_t)3 * 64 * 49152 * 2);   // 18 MB (3 role images)
  float* G0 = (float*)alloc((size_t)V * G * 4);        // 3 MB
  f16* emb16 = (f16*)alloc((size_t)V * H * 2);
  f16* wih0_16 = (f16*)alloc((size_t)G * H * 2);       // 6 MB
  f16* wout16 = (f16*)alloc((size_t)V * H * 2);
  f16* h1ring = (f16*)alloc((size_t)128 * 65536 * 2);  // 16.8 MB (depth-128)
  f16* h2ring = (f16*)alloc((size_t)513 * 65536 * 2);  // 67.2 MB (doubles as y2)
  float* gx2 = (float*)alloc((size_t)8 * 64 * 3072 * 4);  // 6.3 MB (ring-8)
  int* bar = (int*)alloc(65536);  // arrive slots, 64B-strided
  // arrive slots zeroed by pack_h0f (kernel-end writeback publishes).

  // ---- one-time converts / packs / G0 ----
  to_f16_4<<<(V * H / 4 + 255) / 256, 256, 0, stream>>>(emb, emb16, V * H / 4);
  to_f16_4<<<(G * H / 4 + 255) / 256, 256, 0, stream>>>(W_ih, wih0_16,
                                                        G * H / 4);
  to_f16_4<<<(V * H / 4 + 255) / 256, 256, 0, stream>>>(W_out, wout16,
                                                        V * H / 4);
  pack_w<<<4608, 256, 0, stream>>>(W_hh, W_ih, pW);
  pack_h0f<<<512, 256, 0, stream>>>(h0, h1ring, h2ring, bar);
  gemm_f16<0><<<dim3(G / 64, V / 64), 256, 0, stream>>>(emb16, wih0_16, b_ih,
                                                        G0, V, G, H);

  // ---- persistent decoupled pipeline (cooperative: co-residency) ----
  {
    const f16* a0 = pW; const float* a1 = G0; const int* a2 = X;
    const float* a3 = b_hh; const float* a4 = b_ih;
    f16* a5 = h1ring; f16* a6 = h2ring; float* a7 = gx2; int* a8 = bar;
    void* args[] = {&a0, &a1, &a2, &a3, &a4, &a5, &a6, &a7, &a8};
    hipLaunchCooperativeKernel((const void*)gru_persist, dim3(NBLK), dim3(256),
                               args, 0, stream);
  }

  // ---- logits = y2 @ W_out^T + b_out; y2[t] = h2ring slab t+1 ----
  gemm_f16<2><<<dim3(V / 64, T), 256, 0, stream>>>(h2ring + 65536, wout16,
                                                   b_out, out, T * B, V, H);
}